// Round 12
// baseline (258.054 us; speedup 1.0000x reference)
//
#include <hip/hip_runtime.h>
#include <cstdint>
#include <cstddef>

#define S_LEN 4096
#define DIM   1024
#define NH    16
#define HD    64
#define QKV_N 3072
#define NSPLIT 4

typedef __attribute__((ext_vector_type(8))) short short8;     // 8 bf16
typedef __attribute__((ext_vector_type(4))) float f32x4;      // MFMA C/D frag
typedef __attribute__((ext_vector_type(4))) unsigned short ushort4v;
typedef __attribute__((ext_vector_type(2))) unsigned int uint2v;
typedef __attribute__((ext_vector_type(4))) _Float16 half4;   // 16x16x16 A/B frag
typedef __attribute__((ext_vector_type(2))) _Float16 half2v;

__device__ inline unsigned short f2bf(float x) {   // RNE float->bf16
    unsigned int u = __builtin_bit_cast(unsigned int, x);
    u += 0x7fffu + ((u >> 16) & 1u);
    return (unsigned short)(u >> 16);
}
__device__ inline float bf2f(unsigned short u) {
    return __builtin_bit_cast(float, (unsigned int)u << 16);
}
// pack 2 floats -> 2 bf16 (round-half-up): 2 v_add + 1 v_perm
__device__ inline unsigned int pack2_bf16_rh(float lo, float hi) {
    unsigned int a = __builtin_bit_cast(unsigned int, lo) + 0x8000u;
    unsigned int b = __builtin_bit_cast(unsigned int, hi) + 0x8000u;
    return __builtin_amdgcn_perm(b, a, 0x07060302u);   // D = {b.hi16, a.hi16}
}

// async global->LDS, 16B per lane; LDS dest = wave-uniform base + lane*16
__device__ inline void gl_lds16(const void* g, void* l) {
    __builtin_amdgcn_global_load_lds(
        (const __attribute__((address_space(1))) void*)g,
        (__attribute__((address_space(3))) void*)l, 16, 0, 0);
}

// ---------------------------------------------------------------------------
// bf16 MFMA GEMM (m97 structure): C = A @ Bt^T + bias.
// ---------------------------------------------------------------------------
template <bool BF16OUT>
__global__ __launch_bounds__(256) void gemm_mfma_kernel(
    const unsigned short* __restrict__ A,
    const unsigned short* __restrict__ Bt,
    const float* __restrict__ bias,
    void* __restrict__ Cv,
    int M, int N, int K)
{
    __shared__ unsigned short As[128 * 32];   // [m][k], k contiguous (no pad: glds)
    __shared__ unsigned short Bs[128 * 32];   // [n][k]

    const int t    = threadIdx.x;
    const int w    = t >> 6;
    const int lane = t & 63;
    const int ln   = lane & 15;
    const int quad = lane >> 4;
    const int bm   = blockIdx.y * 128;
    const int bn   = blockIdx.x * 128;
    const int wm   = (w & 1) * 64;
    const int wn   = (w >> 1) * 64;

    f32x4 acc[4][4];
#pragma unroll
    for (int i = 0; i < 4; ++i)
#pragma unroll
        for (int j = 0; j < 4; ++j) acc[i][j] = (f32x4){0.f, 0.f, 0.f, 0.f};

    const int lr = lane >> 2;
    const int lc = (lane & 3) * 8;
    const unsigned short* ga = A  + (size_t)(bm + w * 32 + lr) * K + lc;
    const unsigned short* gb = Bt + (size_t)(bn + w * 32 + lr) * K + lc;
    unsigned short* la = &As[(w * 32) * 32];
    unsigned short* lb = &Bs[(w * 32) * 32];

    for (int k0 = 0; k0 < K; k0 += 32) {
        gl_lds16(ga,            la);
        gl_lds16(ga + 16 * K,   la + 16 * 32);
        gl_lds16(gb,            lb);
        gl_lds16(gb + 16 * K,   lb + 16 * 32);
        ga += 32; gb += 32;
        __syncthreads();

        short8 af[4], bf[4];
#pragma unroll
        for (int i = 0; i < 4; ++i)
            af[i] = *(const short8*)&As[(wm + i * 16 + ln) * 32 + quad * 8];
#pragma unroll
        for (int j = 0; j < 4; ++j)
            bf[j] = *(const short8*)&Bs[(wn + j * 16 + ln) * 32 + quad * 8];
#pragma unroll
        for (int i = 0; i < 4; ++i)
#pragma unroll
            for (int j = 0; j < 4; ++j)
                acc[i][j] = __builtin_amdgcn_mfma_f32_16x16x32_bf16(af[i], bf[j], acc[i][j], 0, 0, 0);
        __syncthreads();
    }

#pragma unroll
    for (int j = 0; j < 4; ++j) {
        const int col = bn + wn + j * 16 + ln;
        const float bv = bias[col];
#pragma unroll
        for (int i = 0; i < 4; ++i) {
            const int row0 = bm + wm + i * 16 + quad * 4;
#pragma unroll
            for (int r = 0; r < 4; ++r) {
                const float v = acc[i][j][r] + bv;
                if (BF16OUT)
                    ((unsigned short*)Cv)[(size_t)(row0 + r) * N + col] = f2bf(v);
                else
                    ((float*)Cv)[(size_t)(row0 + r) * N + col] = v;
            }
        }
    }
}

// ---------------------------------------------------------------------------
// Fused prep 1: x->bf16 convert (blocks 0..2047), Wqkv transpose-convert
// (2048..2815), Wo transpose-convert (2816..3071).
// ---------------------------------------------------------------------------
__global__ __launch_bounds__(256) void prep1_kernel(
    const float* __restrict__ x, unsigned short* __restrict__ xb,
    const float* __restrict__ Wqkv, unsigned short* __restrict__ WqkvT,
    const float* __restrict__ Wo, unsigned short* __restrict__ WoT)
{
    __shared__ unsigned short L[64][72];
    const int b = blockIdx.x;
    const int t = threadIdx.x;

    if (b < 2048) {   // convert x
        const size_t i = ((size_t)b * 256 + t) * 8;
        float4 a = *(const float4*)(x + i);
        float4 c = *(const float4*)(x + i + 4);
        short8 p = { (short)f2bf(a.x), (short)f2bf(a.y), (short)f2bf(a.z), (short)f2bf(a.w),
                     (short)f2bf(c.x), (short)f2bf(c.y), (short)f2bf(c.z), (short)f2bf(c.w) };
        *(short8*)(xb + i) = p;
        return;
    }
    const float* W;
    unsigned short* Wt;
    int N, n0, k0;
    if (b < 2816) {   // Wqkv: K=1024 x N=3072
        const int wb = b - 2048;
        W = Wqkv; Wt = WqkvT; N = QKV_N;
        n0 = (wb % 48) * 64; k0 = (wb / 48) * 64;
    } else {          // Wo: 1024 x 1024
        const int wb = b - 2816;
        W = Wo; Wt = WoT; N = DIM;
        n0 = (wb & 15) * 64; k0 = (wb >> 4) * 64;
    }
    const int kr = t >> 2, cb = (t & 3) * 16;
    const float* wp = W + (size_t)(k0 + kr) * N + n0 + cb;
#pragma unroll
    for (int u = 0; u < 16; u += 4) {
        float4 v = *(const float4*)(wp + u);
        ushort4v p = { f2bf(v.x), f2bf(v.y), f2bf(v.z), f2bf(v.w) };
        *(ushort4v*)&L[kr][cb + u] = p;
    }
    __syncthreads();
    const int nr = t >> 2, kb = (t & 3) * 16;
    short8 lo, hi;
#pragma unroll
    for (int u = 0; u < 8; ++u) lo[u] = (short)L[kb + u][nr];
#pragma unroll
    for (int u = 0; u < 8; ++u) hi[u] = (short)L[kb + 8 + u][nr];
    unsigned short* op = Wt + (size_t)(n0 + nr) * 1024 + k0 + kb;   // K is always 1024
    *(short8*)op       = lo;
    *(short8*)(op + 8) = hi;
}

// ---------------------------------------------------------------------------
// Fused prep 2: RoPE q/k (blocks 0..2047) + V transpose -> f16 (2048..3071).
// ---------------------------------------------------------------------------
__global__ __launch_bounds__(256) void prep2_kernel(
    const unsigned short* __restrict__ qkvb,
    unsigned short* __restrict__ Qb,
    unsigned short* __restrict__ Kb,
    unsigned short* __restrict__ Vt)   // holds f16 bits
{
    __shared__ unsigned short L[64][72];
    const int b = blockIdx.x;
    const int t = threadIdx.x;

    if (b < 2048) {   // RoPE
        const int idx = b * 256 + t;          // S*128 total
        const int j   = (idx & 127) * 4;
        const int s   = idx >> 7;
        const unsigned short* row = qkvb + (size_t)s * QKV_N;
        unsigned short* qo = Qb + (size_t)s * DIM;
        unsigned short* ko = Kb + (size_t)s * DIM;
        const float sf = (float)s;
        const float QSCALE = 0.18033688011112042f;   // 0.125 * log2(e)
        const float C1 = -0.025952563241307517f;     // -log2(10000)/512
        const float INV2PI = 0.15915494309189535f;

        float cs[4], sn[4];
#pragma unroll
        for (int e = 0; e < 4; ++e) {
            const float invf2pi = exp2f((float)(j + e) * C1) * INV2PI;
            float rev = sf * invf2pi;
            rev -= floorf(rev);
            sn[e] = __builtin_amdgcn_sinf(rev);
            cs[e] = __builtin_amdgcn_cosf(rev);
        }
        ushort4v q1 = *(const ushort4v*)(row + j);
        ushort4v q2 = *(const ushort4v*)(row + 512 + j);
        ushort4v k1 = *(const ushort4v*)(row + DIM + j);
        ushort4v k2 = *(const ushort4v*)(row + DIM + 512 + j);
        ushort4v qa, qb4, ka, kb4;
#pragma unroll
        for (int e = 0; e < 4; ++e) {
            const float x1 = bf2f(q1[e]), x2 = bf2f(q2[e]);
            const float y1 = bf2f(k1[e]), y2 = bf2f(k2[e]);
            qa[e]  = f2bf((x1 * cs[e] - x2 * sn[e]) * QSCALE);
            qb4[e] = f2bf((x2 * cs[e] + x1 * sn[e]) * QSCALE);
            ka[e]  = f2bf(y1 * cs[e] - y2 * sn[e]);
            kb4[e] = f2bf(y2 * cs[e] + y1 * sn[e]);
        }
        *(ushort4v*)(qo + j)       = qa;
        *(ushort4v*)(qo + 512 + j) = qb4;
        *(ushort4v*)(ko + j)       = ka;
        *(ushort4v*)(ko + 512 + j) = kb4;
        return;
    }

    // V transpose: 64x64 tile, bf16 -> f16 output
    const int vb = b - 2048;
    const int c0 = (vb & 15) * 64;
    const int bs = (vb >> 4) * 64;
    const int sl = t >> 2, cb = (t & 3) * 16;
    const unsigned short* vp = qkvb + (size_t)(bs + sl) * QKV_N + 2 * DIM + c0 + cb;
    *(short8*)&L[sl][cb]     = *(const short8*)vp;
    *(short8*)&L[sl][cb + 8] = *(const short8*)(vp + 8);
    __syncthreads();
    const int cl = t >> 2, sb = (t & 3) * 16;
    short8 lo, hi;
#pragma unroll
    for (int u = 0; u < 8; ++u)
        lo[u] = (short)__builtin_bit_cast(unsigned short, (_Float16)bf2f(L[sb + u][cl]));
#pragma unroll
    for (int u = 0; u < 8; ++u)
        hi[u] = (short)__builtin_bit_cast(unsigned short, (_Float16)bf2f(L[sb + 8 + u][cl]));
    unsigned short* op = Vt + (size_t)(c0 + cl) * S_LEN + bs + sb;
    *(short8*)op       = lo;
    *(short8*)(op + 8) = hi;
}

// ---------------------------------------------------------------------------
// MFMA flash attention v5 = v4 with 128-q tiles (2 strips/wave).
//  Rationale (R11 counters): LDS pipe ~70 of 92 us. K/V staging and Vs frags
//  are per-TILE costs; widening q per block to 128 halves LDS bytes per unit
//  work. Vs frags (16 x b64) loaded ONCE per tile into registers and reused
//  by both strips; Ks re-read per strip (scales with work).
//  - Wave w owns q rows {q0 + s*64 + w*16 + ln} for strips s=0,1.
//  - S^T = K·Q^T (16x16x32 bf16); P=exp2(S) straight into 16x16x16f16 B-frag
//    (layout coincidence verified R10/R11); O^T per strip in registers.
//  - No online max; l per-lane per strip, 2 shfl at epilogue.
//  - Split-K x4, paired phases (qt = 31-p then p): ~16.5 uniform iters/block.
//  - grid 16 x 4 x 16 = 1024 blocks = 4/CU, matching 4-waves/SIMD VGPR cap.
// ---------------------------------------------------------------------------
__global__ __launch_bounds__(256) void attn_mfma_kernel(
    const unsigned short* __restrict__ Qb,
    const unsigned short* __restrict__ Kb,
    const unsigned short* __restrict__ Vt,   // f16 bits, [d][s]
    unsigned short* __restrict__ Opb,  // [NSPLIT][S][DIM] bf16 partial O
    float* __restrict__ lp)            // [NSPLIT][NH][S] fp32 partial l
{
    __shared__ unsigned short Ks[64][72];   // [key][d] bf16
    __shared__ unsigned short Vs[64][72];   // [d][key] f16

    const int t    = threadIdx.x;
    const int w    = t >> 6;
    const int lane = t & 63;
    const int ln   = lane & 15;
    const int quad = lane >> 4;
    const int p    = blockIdx.x;     // 0..15
    const int hf   = blockIdx.y;     // 0..3 split-K quarter
    const int h    = blockIdx.z;

    const int srow = t >> 2;          // staging row (key for Ks, d for Vs)
    const int scol = (t & 3) * 16;    // staging 16-ushort chunk

    for (int phase = 0; phase < 2; ++phase) {
        const int qt  = phase == 0 ? (31 - p) : p;
        const int q0  = qt * 128;
        const int nkt = 2 * (qt + 1);
        const int kt_begin = (nkt * hf) >> 2;
        const int kt_end   = (nkt * (hf + 1)) >> 2;

        // Q B-frags for both strips (4 x short8 x ... = 16 VGPRs)
        short8 qf[2][2];
#pragma unroll
        for (int s = 0; s < 2; ++s) {
            const unsigned short* qp = Qb + (size_t)(q0 + s * 64 + w * 16 + ln) * DIM
                                          + h * HD + quad * 8;
            qf[s][0] = *(const short8*)qp;
            qf[s][1] = *(const short8*)(qp + 32);
        }

        f32x4 o[2][4];   // o[s][db]: O^T[d=db*16+quad*4+r][q of strip s]
#pragma unroll
        for (int s = 0; s < 2; ++s)
#pragma unroll
            for (int db = 0; db < 4; ++db) o[s][db] = (f32x4){0.f, 0.f, 0.f, 0.f};
        float lac[2] = {0.f, 0.f};

        // prefetch first tile of this block's range (addr in-bounds even if empty)
        short8 kr0, kr1, vr0, vr1;
        {
            const int k0 = kt_begin * 64;
            const unsigned short* kp = Kb + (size_t)(k0 + srow) * DIM + h * HD + scol;
            kr0 = *(const short8*)kp;       kr1 = *(const short8*)(kp + 8);
            const unsigned short* vp = Vt + (size_t)(h * HD + srow) * S_LEN + k0 + scol;
            vr0 = *(const short8*)vp;       vr1 = *(const short8*)(vp + 8);
        }

        for (int kt = kt_begin; kt < kt_end; ++kt) {
            __syncthreads();   // prior tile's Ks/Vs reads complete
            *(short8*)&Ks[srow][scol]     = kr0;
            *(short8*)&Ks[srow][scol + 8] = kr1;
            *(short8*)&Vs[srow][scol]     = vr0;
            *(short8*)&Vs[srow][scol + 8] = vr1;
            if (kt + 1 < kt_end) {   // prefetch next tile (overlaps barrier+compute)
                const int k1 = (kt + 1) * 64;
                const unsigned short* kp = Kb + (size_t)(k1 + srow) * DIM + h * HD + scol;
                kr0 = *(const short8*)kp;   kr1 = *(const short8*)(kp + 8);
                const unsigned short* vp = Vt + (size_t)(h * HD + srow) * S_LEN + k1 + scol;
                vr0 = *(const short8*)vp;   vr1 = *(const short8*)(vp + 8);
            }
            __syncthreads();   // staging visible

            // Vs fragments once per tile (reused by both strips): 16 x b64
            half4 vf[4][4];
#pragma unroll
            for (int db = 0; db < 4; ++db)
#pragma unroll
                for (int kb = 0; kb < 4; ++kb)
                    vf[db][kb] = *(const half4*)&Vs[db * 16 + ln][kb * 16 + quad * 4];

            const bool need_mask = (kt >= nkt - 2);

#pragma unroll
            for (int s = 0; s < 2; ++s) {
                const int qg = q0 + s * 64 + w * 16 + ln;
#pragma unroll
                for (int kb = 0; kb < 4; ++kb) {
                    // S^T chunk: sc[r] = S(key=kt*64+kb*16+quad*4+r, q=qg)
                    f32x4 sc = (f32x4){0.f, 0.f, 0.f, 0.f};
#pragma unroll
                    for (int kk = 0; kk < 2; ++kk) {
                        short8 kf = *(const short8*)&Ks[kb * 16 + ln][kk * 32 + quad * 8];
                        sc = __builtin_amdgcn_mfma_f32_16x16x32_bf16(kf, qf[s][kk], sc, 0, 0, 0);
                    }
                    if (need_mask) {
                        const int key = kt * 64 + kb * 16 + quad * 4;
#pragma unroll
                        for (int r = 0; r < 4; ++r)
                            if (key + r > qg) sc[r] = -1e30f;
                    }
                    // exp2 -> in-register P fragment (f16)
                    const float p0 = exp2f(sc[0]);
                    const float p1 = exp2f(sc[1]);
                    const float p2 = exp2f(sc[2]);
                    const float p3 = exp2f(sc[3]);
                    lac[s] += (p0 + p1) + (p2 + p3);
                    half2v lo2 = __builtin_bit_cast(half2v, __builtin_amdgcn_cvt_pkrtz(p0, p1));
                    half2v hi2 = __builtin_bit_cast(half2v, __builtin_amdgcn_cvt_pkrtz(p2, p3));
                    half4 pf = (half4){lo2[0], lo2[1], hi2[0], hi2[1]};
                    // O^T += V^T·P^T
#pragma unroll
                    for (int db = 0; db < 4; ++db)
                        o[s][db] = __builtin_amdgcn_mfma_f32_16x16x16f16(vf[db][kb], pf, o[s][db], 0, 0, 0);
                }
            }
        }

        // ---- phase epilogue (no LDS, no barriers) ----
#pragma unroll
        for (int s = 0; s < 2; ++s) {
            lac[s] += __shfl_xor(lac[s], 16);
            lac[s] += __shfl_xor(lac[s], 32);

            unsigned short* op = Opb + ((size_t)hf * S_LEN + q0 + s * 64 + w * 16 + ln) * DIM
                                     + h * HD + quad * 4;
#pragma unroll
            for (int db = 0; db < 4; ++db) {
                uint2v pk = { pack2_bf16_rh(o[s][db][0], o[s][db][1]),
                              pack2_bf16_rh(o[s][db][2], o[s][db][3]) };
                *(uint2v*)(op + db * 16) = pk;
            }
            if (quad == 0)
                lp[((size_t)hf * NH + h) * S_LEN + q0 + s * 64 + w * 16 + ln] = lac[s];
        }
    }
}

// ---------------------------------------------------------------------------
// Combine split-K partials: attnb = (Σ O_i) / (Σ l_i), bf16 out.
// ---------------------------------------------------------------------------
__global__ __launch_bounds__(256) void combine_kernel(
    const unsigned short* __restrict__ Opb, const float* __restrict__ lp,
    unsigned short* __restrict__ attnb)
{
    const int row = blockIdx.x;
    const int t   = threadIdx.x;
    const int d   = t * 4;
    const int h   = t >> 4;
    f32x4 acc = (f32x4){0.f, 0.f, 0.f, 0.f};
    float l = 0.f;
#pragma unroll
    for (int i = 0; i < NSPLIT; ++i) {
        ushort4v a = *(const ushort4v*)&Opb[((size_t)i * S_LEN + row) * DIM + d];
#pragma unroll
        for (int e = 0; e < 4; ++e) acc[e] += bf2f(a[e]);
        l += lp[((size_t)i * NH + h) * S_LEN + row];
    }
    const float inv = 1.0f / l;
    ushort4v o;
#pragma unroll
    for (int e = 0; e < 4; ++e) o[e] = f2bf(acc[e] * inv);
    *(ushort4v*)&attnb[(size_t)row * DIM + d] = o;
}

// ---------------------------------------------------------------------------
__global__ __launch_bounds__(256) void ln_kernel(
    const float* __restrict__ in, const float* __restrict__ gamma,
    const float* __restrict__ beta, float* __restrict__ out)
{
    const int row = blockIdx.x;
    const int t = threadIdx.x;
    const float4 v = *(const float4*)&in[(size_t)row * DIM + t * 4];
    float s  = v.x + v.y + v.z + v.w;
    float sq = v.x * v.x + v.y * v.y + v.z * v.z + v.w * v.w;
#pragma unroll
    for (int off = 1; off < 64; off <<= 1) {
        s  += __shfl_xor(s, off);
        sq += __shfl_xor(sq, off);
    }
    __shared__ float red[8];
    const int wv = t >> 6, ln = t & 63;
    if (ln == 0) { red[wv] = s; red[4 + wv] = sq; }
    __syncthreads();
    s  = red[0] + red[1] + red[2] + red[3];
    sq = red[4] + red[5] + red[6] + red[7];
    const float mu  = s * (1.0f / DIM);
    const float var = sq * (1.0f / DIM) - mu * mu;
    const float rs  = rsqrtf(var + 1e-5f);
    const float4 g = *(const float4*)&gamma[t * 4];
    const float4 b = *(const float4*)&beta[t * 4];
    float4 o = { (v.x - mu) * rs * g.x + b.x,
                 (v.y - mu) * rs * g.y + b.y,
                 (v.z - mu) * rs * g.z + b.z,
                 (v.w - mu) * rs * g.w + b.w };
    *(float4*)&out[(size_t)row * DIM + t * 4] = o;
}

// ---------------------------------------------------------------------------
extern "C" void kernel_launch(void* const* d_in, const int* in_sizes, int n_in,
                              void* d_out, int out_size, void* d_ws, size_t ws_size,
                              hipStream_t stream)
{
    const float* x     = (const float*)d_in[0];
    const float* Wqkv  = (const float*)d_in[1];
    const float* bqkv  = (const float*)d_in[2];
    const float* Wo    = (const float*)d_in[3];
    const float* bo    = (const float*)d_in[4];
    const float* gamma = (const float*)d_in[5];
    const float* beta  = (const float*)d_in[6];
    float* out = (float*)d_out;

    // ws layout (MB):
    //   [0,8):   attnb bf16 (combine out)      [0,24): qkvb bf16 (early)
    //   [8,40):  Opb bf16 partials [4][S][DIM] -> later proj fp32 at [8,24)
    //   [40,41): lp fp32 partials [4][NH][S]
    //   [48,56): Qb | [56,64): Kb | [64,72): Vt (f16)
    //   [72,80): xb | [80,86): WqkvT | [86,88): WoT
    char* base = (char*)d_ws;
    unsigned short* qkvb  = (unsigned short*)base;
    unsigned short* attnb = (unsigned short*)base;
    unsigned short* Opb   = (unsigned short*)(base + (size_t)8 * 1024 * 1024);
    float* proj = (float*)(base + (size_t)8 * 1024 * 1024);
    float* lp   = (float*)(base + (size_t)40 * 1024 * 1024);
    unsigned short* Qb    = (unsigned short*)(base + (size_t)48 * 1024 * 1024);
    unsigned short* Kb    = (unsigned short*)(base + (size_t)56 * 1024 * 1024);
    unsigned short* Vt    = (unsigned short*)(base + (size_t)64 * 1024 * 1024);
    unsigned short* xb    = (unsigned short*)(base + (size_t)72 * 1024 * 1024);
    unsigned short* WqkvT = (unsigned short*)(base + (size_t)80 * 1024 * 1024);
    unsigned short* WoT   = (unsigned short*)(base + (size_t)86 * 1024 * 1024);

    prep1_kernel<<<3072, 256, 0, stream>>>(x, xb, Wqkv, WqkvT, Wo, WoT);

    gemm_mfma_kernel<true><<<dim3(QKV_N / 128, S_LEN / 128), 256, 0, stream>>>(
        xb, WqkvT, bqkv, qkvb, S_LEN, QKV_N, DIM);

    prep2_kernel<<<3072, 256, 0, stream>>>(qkvb, Qb, Kb, Vt);

    attn_mfma_kernel<<<dim3(16, NSPLIT, NH), 256, 0, stream>>>(Qb, Kb, Vt, Opb, lp);

    combine_kernel<<<S_LEN, 256, 0, stream>>>(Opb, lp, attnb);

    gemm_mfma_kernel<false><<<dim3(DIM / 128, S_LEN / 128), 256, 0, stream>>>(
        attnb, WoT, bo, proj, S_LEN, DIM, DIM);

    ln_kernel<<<S_LEN, 256, 0, stream>>>(proj, gamma, beta, out);
}